// Round 16
// baseline (107.391 us; speedup 1.0000x reference)
//
#include <hip/hip_runtime.h>

#define NN 100000
#define NE 1600000
#define ALPHA 0.2f

#define BSH   9                          // 512 nodes per bucket
#define NPBK  512                        // nodes per bucket
#define NBUCK ((NN + NPBK - 1) / NPBK)   // 196 buckets
#define NPB   256                        // partition blocks
#define CHUNK ((NE + NPB - 1) / NPB)     // 6250 edges per block
#define MAXB  16384                      // packed slots per bucket (90-sigma headroom)

#define MTILES (NN / 16)                 // 6250 (NN % 16 == 0)
#define TSPLIT 3600                      // tiles in kernel A (rest in kernel B)
#define NA     (TSPLIT / 4)              // 900 filler blocks in A (4 tiles each)
#define NB     (((MTILES - TSPLIT) + 7) / 8)  // 332 filler blocks in B (8 tiles)

typedef __attribute__((ext_vector_type(8))) short  short8;
typedef __attribute__((ext_vector_type(4))) float  f32x4;

// ---------------- bf16 helpers (RNE pack, cheap unpack) ---------------------
__device__ __forceinline__ unsigned short f2bf(float f) {
    unsigned int u = __builtin_bit_cast(unsigned int, f);
    u += 0x7FFFu + ((u >> 16) & 1u);
    return (unsigned short)(u >> 16);
}
__device__ __forceinline__ float bflo(unsigned int u) {
    return __builtin_bit_cast(float, u << 16);
}
__device__ __forceinline__ float bfhi(unsigned int u) {
    return __builtin_bit_cast(float, u & 0xFFFF0000u);
}

// ---------------- DPP adds (all VALU, no DS pipe) ---------------------------
template<int CTRL>
__device__ __forceinline__ float dpp_add(float x) {
    int y = __builtin_amdgcn_update_dpp(0, __builtin_bit_cast(int, x),
                                        CTRL, 0xF, 0xF, true);
    return x + __builtin_bit_cast(float, y);
}

// ---------------- 512-thread block exclusive scan ---------------------------
__device__ __forceinline__ int block_excl_scan_512(int val, int* lds8) {
    const int lane = threadIdx.x & 63;
    const int wid  = threadIdx.x >> 6;   // 0..7
    int incl = val;
    #pragma unroll
    for (int off = 1; off < 64; off <<= 1) {
        int t = __shfl_up(incl, off);
        if (lane >= off) incl += t;
    }
    if (lane == 63) lds8[wid] = incl;
    __syncthreads();
    int wbase = 0;
    #pragma unroll
    for (int w = 0; w < 8; w++) if (w < wid) wbase += lds8[w];
    __syncthreads();
    return wbase + incl - val;
}

// ---------------------------------------------------------------------------
// Transform helpers — pure bf16 MFMA: acc = bf16(A) · bf16(B).  B packed once
// per block into 16 KB LDS. Error: ~2e-3 per output on top of bf16 storage
// rounding — within the 0.0806 budget (measured 0.031 with one-sided rounding).
// C/D layout (HW-verified): col=lane&15, row=(lane>>4)*4+reg.
// ---------------------------------------------------------------------------
__device__ __forceinline__ void transform_prep(
    const float* __restrict__ Wq, const float* __restrict__ bq,
    const float* __restrict__ Wv, const float* __restrict__ bv,
    short8 (*sB)[8][64], float* sbias, int tid, int nthr)
{
    if (tid < 64)       sbias[tid] = bq[tid];
    else if (tid < 128) sbias[tid] = bv[tid - 64];
    for (int slot = tid; slot < 2 * 8 * 64; slot += nthr) {
        const int lane  = slot & 63;
        const int ntile = (slot >> 6) & 7;
        const int kstep = slot >> 9;
        const int j     = ntile * 16 + (lane & 15);
        const int kbase = kstep * 32 + (lane >> 4) * 8;
        const float* W  = (j < 64) ? Wq : Wv;
        const int jj    = j & 63;
        short8 hi;
        #pragma unroll
        for (int r = 0; r < 8; r++)
            hi[r] = (short)f2bf(W[(kbase + r) * 64 + jj]);
        sB[kstep][ntile][lane] = hi;
    }
}

__device__ __forceinline__ void transform_tile(
    const float* __restrict__ nf,
    unsigned short* __restrict__ qbf, unsigned short* __restrict__ vbf,
    short8 (*sB)[8][64], const float* sbias, int wt, int lane)
{
    const int row = wt * 16 + (lane & 15);
    short8 ah[2];
    #pragma unroll
    for (int s = 0; s < 2; s++) {
        const float* ap = nf + (size_t)row * 64 + s * 32 + (lane >> 4) * 8;
        #pragma unroll
        for (int r = 0; r < 8; r++)
            ah[s][r] = (short)f2bf(ap[r]);
    }
    #pragma unroll
    for (int nt = 0; nt < 8; nt++) {
        f32x4 acc = {0.f, 0.f, 0.f, 0.f};
        acc = __builtin_amdgcn_mfma_f32_16x16x32_bf16(ah[0], sB[0][nt][lane], acc, 0, 0, 0);
        acc = __builtin_amdgcn_mfma_f32_16x16x32_bf16(ah[1], sB[1][nt][lane], acc, 0, 0, 0);
        const int col = nt * 16 + (lane & 15);
        const float b = sbias[col];
        unsigned short* outp = (col < 64) ? qbf : vbf;
        const int jj    = col & 63;
        const int rbase = wt * 16 + (lane >> 4) * 4;
        #pragma unroll
        for (int r = 0; r < 4; r++)
            outp[(size_t)(rbase + r) * 64 + jj] = f2bf(acc[r] + b);
    }
}

// ---------------------------------------------------------------------------
// Kernel A: blocks 0..NPB-1 = single-pass direct partition (LDS count ->
// one global atomicAdd per (block,bucket) run-reservation -> packed write
// into the bucket's fixed region). Remaining blocks: transform tiles 0..TSPLIT.
// gcur[bk] starts at 0 (memset) and holds the bucket size afterwards.
// ---------------------------------------------------------------------------
__global__ __launch_bounds__(256) void kA_partition_tf(
    const float* __restrict__ nf, const float* __restrict__ Wq, const float* __restrict__ bq,
    const float* __restrict__ Wv, const float* __restrict__ bv,
    unsigned short* __restrict__ qbf, unsigned short* __restrict__ vbf,
    const int* __restrict__ esrc, const int* __restrict__ etgt,
    int* __restrict__ gcur, unsigned int* __restrict__ packed)
{
    __shared__ short8 sB[2][8][64];      // 16 KB (transform branch)
    __shared__ float  sbias[128];
    __shared__ int    h[NBUCK];
    const int tid = threadIdx.x;
    const int bid = blockIdx.x;

    if (bid < NPB) {
        // pass 1: per-bucket counts for this chunk
        for (int i = tid; i < NBUCK; i += 256) h[i] = 0;
        __syncthreads();
        const int e0 = bid * CHUNK;
        const int e1 = min(e0 + CHUNK, NE);
        for (int e = e0 + tid; e < e1; e += 256)
            atomicAdd(&h[etgt[e] >> BSH], 1);
        __syncthreads();
        // reserve a contiguous run per bucket; h becomes the local cursor
        for (int i = tid; i < NBUCK; i += 256) {
            int c = h[i];
            h[i] = c ? atomicAdd(&gcur[i], c) : 0;
        }
        __syncthreads();
        // pass 2: write packed entries into reserved runs
        for (int e = e0 + tid; e < e1; e += 256) {
            int t = etgt[e], s = esrc[e];
            int bk = t >> BSH;
            int o = atomicAdd(&h[bk], 1);
            packed[(size_t)bk * MAXB + o] = (unsigned)s | ((unsigned)(t & (NPBK - 1)) << 17);
        }
        return;
    }

    transform_prep(Wq, bq, Wv, bv, sB, sbias, tid, 256);
    __syncthreads();
    const int wt = (bid - NPB) * 4 + (tid >> 6);       // tiles 0..TSPLIT-1
    if (wt < TSPLIT) transform_tile(nf, qbf, vbf, sB, sbias, wt, tid & 63);
}

// ---------------------------------------------------------------------------
// Kernel B (512 threads): blocks 0..NBUCK-1 = bucket counting-sort.
// Each block self-derives its global CSR base by scanning gcur (196 sizes),
// then sorts its packed region -> offs + ssrc. Remaining blocks: transform
// tiles TSPLIT..MTILES (8 tiles/block).
// ---------------------------------------------------------------------------
__global__ __launch_bounds__(512) void kB_csr_tf(
    const float* __restrict__ nf, const float* __restrict__ Wq, const float* __restrict__ bq,
    const float* __restrict__ Wv, const float* __restrict__ bv,
    unsigned short* __restrict__ qbf, unsigned short* __restrict__ vbf,
    const unsigned int* __restrict__ packed, const int* __restrict__ gcur,
    int* __restrict__ offs, int* __restrict__ ssrc)
{
    __shared__ short8 sB[2][8][64];      // 16 KB
    __shared__ float  sbias[128];
    __shared__ int    cnt[NPBK];
    __shared__ int    lds8[8];
    __shared__ int    sS0, sSZ;
    const int tid = threadIdx.x;
    const int bid = blockIdx.x;

    if (bid < NBUCK) {
        // global CSR base for this bucket = exclusive scan of bucket sizes
        int val = (tid < NBUCK) ? gcur[tid] : 0;
        int ex  = block_excl_scan_512(val, lds8);
        if (tid == bid) { sS0 = ex; sSZ = val; }
        if (bid == 0 && tid == 0) offs[NN] = NE;
        __syncthreads();
        const int s0 = sS0;
        const int sz = sSZ;
        const unsigned int* mypack = packed + (size_t)bid * MAXB;

        cnt[tid] = 0;
        __syncthreads();
        for (int e = tid; e < sz; e += 512)
            atomicAdd(&cnt[mypack[e] >> 17], 1);
        __syncthreads();
        int a  = cnt[tid];
        int ex2 = block_excl_scan_512(a, lds8);
        const int node = (bid << BSH) + tid;
        const int g = s0 + ex2;
        if (node < NN) offs[node] = g;
        __syncthreads();
        cnt[tid] = g;                    // becomes cursor
        __syncthreads();
        for (int e = tid; e < sz; e += 512) {
            unsigned p = mypack[e];
            int pos = atomicAdd(&cnt[p >> 17], 1);
            ssrc[pos] = (int)(p & 0x1FFFFu);
        }
        return;
    }

    transform_prep(Wq, bq, Wv, bv, sB, sbias, tid, 512);
    __syncthreads();
    const int wt = TSPLIT + (bid - NBUCK) * 8 + (tid >> 6);
    if (wt < MTILES) transform_tile(nf, qbf, vbf, sB, sbias, wt, tid & 63);
}

// ---------------------------------------------------------------------------
// Gather kernel (UNCHANGED — at the random-gather memory wall):
// one wave per node; 8 lanes per edge (dwordx4 = 8 bf16 channels per lane),
// 8 edge slots, 2-stage rotation. Head logit reduce = ONE dpp add (lane^1).
// ---------------------------------------------------------------------------
__device__ __forceinline__ uint4 ldraw16(const unsigned short* __restrict__ vb,
                                         int src, int s8) {
    return *(const uint4*)((const char*)vb + ((size_t)src << 7) + s8 * 16);
}

__global__ __launch_bounds__(256) void gather_kernel(
    const unsigned short* __restrict__ qb, const unsigned short* __restrict__ vb,
    const float* __restrict__ ak,   // [16][4] row-major: ak[c*4+h]
    const int* __restrict__ offs, const int* __restrict__ ssrc,
    float* __restrict__ out)
{
    const int node = (blockIdx.x * 256 + threadIdx.x) >> 6;
    const int lane = threadIdx.x & 63;
    if (node >= NN) return;
    const int eslot = lane >> 3;     // edge slot 0..7
    const int s8    = lane & 7;      // channel octet 0..7
    const int h     = s8 >> 1;       // head 0..3

    const int start = offs[node];
    const int end   = offs[node + 1];

    if (start >= end) {
        if (lane < 8) {
            float4 z{0.f, 0.f, 0.f, 0.f};
            *(float4*)(out + (size_t)node * 64 + s8 * 8)     = z;
            *(float4*)(out + (size_t)node * 64 + s8 * 8 + 4) = z;
        }
        return;
    }
    const int end1 = end - 1;

    const float c6 = 0.6f * 1.44269504088896f;   // leaky + log2e folded
    const float c4 = 0.4f * 1.44269504088896f;
    float a6[8], a4[8];
    #pragma unroll
    for (int j = 0; j < 8; j++) {
        float k = ak[((s8 & 1) * 8 + j) * 4 + h];
        a6[j] = c6 * k;  a4[j] = c4 * k;
    }

    const uint4 qraw = *(const uint4*)((const char*)qb + ((size_t)node << 7) + s8 * 16);
    float q[8];
    q[0] = bflo(qraw.x); q[1] = bfhi(qraw.x);
    q[2] = bflo(qraw.y); q[3] = bfhi(qraw.y);
    q[4] = bflo(qraw.z); q[5] = bfhi(qraw.z);
    q[6] = bflo(qraw.w); q[7] = bfhi(qraw.w);

    int i0 = ssrc[min(start +     eslot, end1)];
    int i1 = ssrc[min(start + 8 + eslot, end1)];
    uint4 rr0 = ldraw16(vb, i0, s8);
    uint4 rr1 = ldraw16(vb, i1, s8);
    int mi0 = ssrc[min(start + 16 + eslot, end1)];
    int mi1 = ssrc[min(start + 24 + eslot, end1)];

    float acc[8] = {0.f, 0.f, 0.f, 0.f, 0.f, 0.f, 0.f, 0.f};
    float ws = 0.f;

    for (int p = start; p < end; p += 16) {
        {
            float v[8];
            v[0] = bflo(rr0.x); v[1] = bfhi(rr0.x);
            v[2] = bflo(rr0.y); v[3] = bfhi(rr0.y);
            v[4] = bflo(rr0.z); v[5] = bfhi(rr0.z);
            v[6] = bflo(rr0.w); v[7] = bfhi(rr0.w);
            rr0 = ldraw16(vb, mi0, s8);
            mi0 = ssrc[min(p + 32 + eslot, end1)];
            float x = 0.f;
            #pragma unroll
            for (int j = 0; j < 8; j++) {
                float f = q[j] + v[j];
                x = fmaf(f, a6[j], x);
                x = fmaf(fabsf(f), a4[j], x);
            }
            x = dpp_add<0xB1>(x);
            float w = (p + eslot < end) ? __builtin_amdgcn_exp2f(x) : 0.f;
            ws += w;
            #pragma unroll
            for (int j = 0; j < 8; j++) acc[j] = fmaf(w, v[j], acc[j]);
        }
        {
            float v[8];
            v[0] = bflo(rr1.x); v[1] = bfhi(rr1.x);
            v[2] = bflo(rr1.y); v[3] = bfhi(rr1.y);
            v[4] = bflo(rr1.z); v[5] = bfhi(rr1.z);
            v[6] = bflo(rr1.w); v[7] = bfhi(rr1.w);
            rr1 = ldraw16(vb, mi1, s8);
            mi1 = ssrc[min(p + 40 + eslot, end1)];
            float x = 0.f;
            #pragma unroll
            for (int j = 0; j < 8; j++) {
                float f = q[j] + v[j];
                x = fmaf(f, a6[j], x);
                x = fmaf(fabsf(f), a4[j], x);
            }
            x = dpp_add<0xB1>(x);
            float w = (p + 8 + eslot < end) ? __builtin_amdgcn_exp2f(x) : 0.f;
            ws += w;
            #pragma unroll
            for (int j = 0; j < 8; j++) acc[j] = fmaf(w, v[j], acc[j]);
        }
    }

    #pragma unroll
    for (int m = 8; m <= 32; m <<= 1) {
        #pragma unroll
        for (int j = 0; j < 8; j++) acc[j] += __shfl_xor(acc[j], m);
        ws += __shfl_xor(ws, m);
    }

    if (lane < 8) {
        float inv = (ws > 0.f) ? __frcp_rn(ws) : 1.0f;
        float r[8];
        #pragma unroll
        for (int j = 0; j < 8; j++) {
            float t = acc[j] * inv;
            r[j] = fmaxf(t, ALPHA * t);
        }
        *(float4*)(out + (size_t)node * 64 + s8 * 8)     = float4{r[0], r[1], r[2], r[3]};
        *(float4*)(out + (size_t)node * 64 + s8 * 8 + 4) = float4{r[4], r[5], r[6], r[7]};
    }
}

extern "C" void kernel_launch(void* const* d_in, const int* in_sizes, int n_in,
                              void* d_out, int out_size, void* d_ws, size_t ws_size,
                              hipStream_t stream) {
    const float* nf   = (const float*)d_in[0];
    const float* Wq   = (const float*)d_in[1];
    const float* bq   = (const float*)d_in[2];
    const float* Wv   = (const float*)d_in[3];
    const float* bv   = (const float*)d_in[4];
    const float* ak   = (const float*)d_in[5];
    const int*   esrc = (const int*)d_in[6];
    const int*   etgt = (const int*)d_in[7];
    float* out = (float*)d_out;

    // workspace layout:
    //   qbf:    NN*64        u16  (12.8 MB)
    //   vbf:    NN*64        u16  (12.8 MB)
    //   offs:   NN+1         i32  (0.4 MB)
    //   ssrc:   NE           i32  (6.4 MB)
    //   packed: NBUCK*MAXB   u32  (12.85 MB)
    //   gcur:   NBUCK        i32
    unsigned short* qbf    = (unsigned short*)d_ws;
    unsigned short* vbf    = qbf + (size_t)NN * 64;
    int*            offs   = (int*)(vbf + (size_t)NN * 64);
    int*            ssrc   = offs + (NN + 1);
    unsigned int*   packed = (unsigned int*)(ssrc + NE);
    int*            gcur   = (int*)(packed + (size_t)NBUCK * MAXB);

    hipMemsetAsync(gcur, 0, NBUCK * sizeof(int), stream);

    kA_partition_tf<<<NPB + NA, 256, 0, stream>>>(nf, Wq, bq, Wv, bv, qbf, vbf,
                                                  esrc, etgt, gcur, packed);
    kB_csr_tf<<<NBUCK + NB, 512, 0, stream>>>(nf, Wq, bq, Wv, bv, qbf, vbf,
                                              packed, gcur, offs, ssrc);
    gather_kernel<<<(NN * 64 + 255) / 256, 256, 0, stream>>>(qbf, vbf, ak, offs, ssrc, out);
}

// Round 17
// 105.424 us; speedup vs baseline: 1.0187x; 1.0187x over previous
//
#include <hip/hip_runtime.h>

#define NN 100000
#define NE 1600000
#define ALPHA 0.2f

#define BSH   9                          // 512 nodes per bucket
#define NPBK  512                        // nodes per bucket
#define NBUCK ((NN + NPBK - 1) / NPBK)   // 196 buckets
#define NPB   256                        // partition / count blocks
#define CHUNK ((NE + NPB - 1) / NPB)     // 6250 edges per block

#define MTILES (NN / 16)                 // 6250 (NN % 16 == 0)

// transform slices across the 4 CSR-stage kernels (proportional to stage time)
#define TB1 0
#define N1  290      // K1: tiles 0..1159        (4 tiles/block, 256 thr)
#define TB2 1160
#define N2  145      // K2: tiles 1160..1739
#define TB3 1740
#define N3  638      // K3: tiles 1740..4291
#define TB4 4292
#define N4  245      // K4: tiles 4292..6249     (8 tiles/block, 512 thr; guard)

typedef __attribute__((ext_vector_type(8))) short  short8;
typedef __attribute__((ext_vector_type(4))) float  f32x4;

// ---------------- bf16 helpers (RNE pack, cheap unpack) ---------------------
__device__ __forceinline__ unsigned short f2bf(float f) {
    unsigned int u = __builtin_bit_cast(unsigned int, f);
    u += 0x7FFFu + ((u >> 16) & 1u);
    return (unsigned short)(u >> 16);
}
__device__ __forceinline__ float bflo(unsigned int u) {
    return __builtin_bit_cast(float, u << 16);
}
__device__ __forceinline__ float bfhi(unsigned int u) {
    return __builtin_bit_cast(float, u & 0xFFFF0000u);
}

// ---------------- DPP adds (all VALU, no DS pipe) ---------------------------
template<int CTRL>
__device__ __forceinline__ float dpp_add(float x) {
    int y = __builtin_amdgcn_update_dpp(0, __builtin_bit_cast(int, x),
                                        CTRL, 0xF, 0xF, true);
    return x + __builtin_bit_cast(float, y);
}

// ---------------- block exclusive scans -------------------------------------
__device__ __forceinline__ int block_excl_scan_256(int val, int* lds4) {
    const int lane = threadIdx.x & 63;
    const int wid  = threadIdx.x >> 6;
    int incl = val;
    #pragma unroll
    for (int off = 1; off < 64; off <<= 1) {
        int t = __shfl_up(incl, off);
        if (lane >= off) incl += t;
    }
    if (lane == 63) lds4[wid] = incl;
    __syncthreads();
    int wbase = 0;
    #pragma unroll
    for (int w = 0; w < 4; w++) if (w < wid) wbase += lds4[w];
    __syncthreads();
    return wbase + incl - val;
}

__device__ __forceinline__ int block_excl_scan_512(int val, int* lds8) {
    const int lane = threadIdx.x & 63;
    const int wid  = threadIdx.x >> 6;   // 0..7
    int incl = val;
    #pragma unroll
    for (int off = 1; off < 64; off <<= 1) {
        int t = __shfl_up(incl, off);
        if (lane >= off) incl += t;
    }
    if (lane == 63) lds8[wid] = incl;
    __syncthreads();
    int wbase = 0;
    #pragma unroll
    for (int w = 0; w < 8; w++) if (w < wid) wbase += lds8[w];
    __syncthreads();
    return wbase + incl - val;
}

// ---------------------------------------------------------------------------
// Transform helpers — pure bf16 MFMA: acc = bf16(A)·bf16(B), 16 KB sB,
// 2 MFMAs/tile (accuracy-neutral vs B-residual: measured absmax unchanged).
// C/D layout (HW-verified): col=lane&15, row=(lane>>4)*4+reg.
// ---------------------------------------------------------------------------
__device__ __forceinline__ void transform_prep(
    const float* __restrict__ Wq, const float* __restrict__ bq,
    const float* __restrict__ Wv, const float* __restrict__ bv,
    short8 (*sB)[8][64], float* sbias, int tid, int nthr)
{
    if (tid < 64)       sbias[tid] = bq[tid];
    else if (tid < 128) sbias[tid] = bv[tid - 64];
    for (int slot = tid; slot < 2 * 8 * 64; slot += nthr) {
        const int lane  = slot & 63;
        const int ntile = (slot >> 6) & 7;
        const int kstep = slot >> 9;
        const int j     = ntile * 16 + (lane & 15);
        const int kbase = kstep * 32 + (lane >> 4) * 8;
        const float* W  = (j < 64) ? Wq : Wv;
        const int jj    = j & 63;
        short8 hi;
        #pragma unroll
        for (int r = 0; r < 8; r++)
            hi[r] = (short)f2bf(W[(kbase + r) * 64 + jj]);
        sB[kstep][ntile][lane] = hi;
    }
}

__device__ __forceinline__ void transform_tile(
    const float* __restrict__ nf,
    unsigned short* __restrict__ qbf, unsigned short* __restrict__ vbf,
    short8 (*sB)[8][64], const float* sbias, int wt, int lane)
{
    const int row = wt * 16 + (lane & 15);
    short8 ah[2];
    #pragma unroll
    for (int s = 0; s < 2; s++) {
        const float* ap = nf + (size_t)row * 64 + s * 32 + (lane >> 4) * 8;
        #pragma unroll
        for (int r = 0; r < 8; r++)
            ah[s][r] = (short)f2bf(ap[r]);
    }
    #pragma unroll
    for (int nt = 0; nt < 8; nt++) {
        f32x4 acc = {0.f, 0.f, 0.f, 0.f};
        acc = __builtin_amdgcn_mfma_f32_16x16x32_bf16(ah[0], sB[0][nt][lane], acc, 0, 0, 0);
        acc = __builtin_amdgcn_mfma_f32_16x16x32_bf16(ah[1], sB[1][nt][lane], acc, 0, 0, 0);
        const int col = nt * 16 + (lane & 15);
        const float b = sbias[col];
        unsigned short* outp = (col < 64) ? qbf : vbf;
        const int jj    = col & 63;
        const int rbase = wt * 16 + (lane >> 4) * 4;
        #pragma unroll
        for (int r = 0; r < 4; r++)
            outp[(size_t)(rbase + r) * 64 + jj] = f2bf(acc[r] + b);
    }
}

// ---------------------------------------------------------------------------
// K1: blocks 0..NPB-1 bucket histogram; rest transform tiles TB1..
// ---------------------------------------------------------------------------
__global__ __launch_bounds__(256) void k1_hist_tf(
    const float* __restrict__ nf, const float* __restrict__ Wq, const float* __restrict__ bq,
    const float* __restrict__ Wv, const float* __restrict__ bv,
    unsigned short* __restrict__ qbf, unsigned short* __restrict__ vbf,
    const int* __restrict__ etgt, int* __restrict__ hist)
{
    __shared__ short8 sB[2][8][64];      // 16 KB
    __shared__ float  sbias[128];
    __shared__ int    h[NBUCK];
    const int tid = threadIdx.x;

    if (blockIdx.x < NPB) {
        const int blk = blockIdx.x;
        for (int i = tid; i < NBUCK; i += 256) h[i] = 0;
        __syncthreads();
        const int e0 = blk * CHUNK;
        const int e1 = min(e0 + CHUNK, NE);
        for (int e = e0 + tid; e < e1; e += 256)
            atomicAdd(&h[etgt[e] >> BSH], 1);
        __syncthreads();
        for (int i = tid; i < NBUCK; i += 256)
            hist[blk * NBUCK + i] = h[i];
        return;
    }

    transform_prep(Wq, bq, Wv, bv, sB, sbias, tid, 256);
    __syncthreads();
    const int wt = TB1 + ((int)blockIdx.x - NPB) * 4 + (tid >> 6);
    if (wt < MTILES) transform_tile(nf, qbf, vbf, sB, sbias, wt, tid & 63);
}

// ---------------------------------------------------------------------------
// K2: blocks 0..NBUCK-1 colbase (self-computes bucket totals); rest transform.
// ---------------------------------------------------------------------------
__global__ __launch_bounds__(256) void k2_colbase_tf(
    const float* __restrict__ nf, const float* __restrict__ Wq, const float* __restrict__ bq,
    const float* __restrict__ Wv, const float* __restrict__ bv,
    unsigned short* __restrict__ qbf, unsigned short* __restrict__ vbf,
    const int* __restrict__ hist,
    int* __restrict__ bbase, int* __restrict__ colbase, int* __restrict__ offs)
{
    __shared__ short8 sB[2][8][64];
    __shared__ float  sbias[128];
    __shared__ int lds4[4];
    __shared__ int sb[256];
    const int t = threadIdx.x;

    if (blockIdx.x < NBUCK) {
        const int bk = blockIdx.x;
        int csum = 0;
        if (t < NBUCK) {
            #pragma unroll 8
            for (int b = 0; b < NPB; b++) csum += hist[b * NBUCK + t];
        }
        int gex = block_excl_scan_256(csum, lds4);
        sb[t] = gex;
        if (t == bk) bbase[bk] = gex;
        if (bk == 0 && t == NBUCK - 1) { bbase[NBUCK] = gex + csum; offs[NN] = NE; }
        __syncthreads();
        const int myBase = sb[bk];
        __syncthreads();
        int val = hist[t * NBUCK + bk];
        int ex  = block_excl_scan_256(val, lds4);
        colbase[t * NBUCK + bk] = myBase + ex;
        return;
    }

    transform_prep(Wq, bq, Wv, bv, sB, sbias, t, 256);
    __syncthreads();
    const int wt = TB2 + ((int)blockIdx.x - NBUCK) * 4 + (t >> 6);
    if (wt < MTILES) transform_tile(nf, qbf, vbf, sB, sbias, wt, t & 63);
}

// ---------------------------------------------------------------------------
// K3: blocks 0..NPB-1 partition; rest transform.
// ---------------------------------------------------------------------------
__global__ __launch_bounds__(256) void k3_partition_tf(
    const float* __restrict__ nf, const float* __restrict__ Wq, const float* __restrict__ bq,
    const float* __restrict__ Wv, const float* __restrict__ bv,
    unsigned short* __restrict__ qbf, unsigned short* __restrict__ vbf,
    const int* __restrict__ esrc, const int* __restrict__ etgt,
    const int* __restrict__ colbase, unsigned int* __restrict__ packed)
{
    __shared__ short8 sB[2][8][64];
    __shared__ float  sbias[128];
    __shared__ int cur[NBUCK];
    const int tid = threadIdx.x;

    if (blockIdx.x < NPB) {
        const int blk = blockIdx.x;
        for (int i = tid; i < NBUCK; i += 256)
            cur[i] = colbase[blk * NBUCK + i];
        __syncthreads();
        const int e0 = blk * CHUNK;
        const int e1 = min(e0 + CHUNK, NE);
        for (int e = e0 + tid; e < e1; e += 256) {
            int t = etgt[e], s = esrc[e];
            int bk = t >> BSH;
            int pos = atomicAdd(&cur[bk], 1);
            packed[pos] = (unsigned)s | ((unsigned)(t & (NPBK - 1)) << 17);
        }
        return;
    }

    transform_prep(Wq, bq, Wv, bv, sB, sbias, tid, 256);
    __syncthreads();
    const int wt = TB3 + ((int)blockIdx.x - NPB) * 4 + (tid >> 6);
    if (wt < MTILES) transform_tile(nf, qbf, vbf, sB, sbias, wt, tid & 63);
}

// ---------------------------------------------------------------------------
// K4 (512 threads): blocks 0..NBUCK-1 bucket counting-sort -> offs+ssrc;
// rest transform (8 tiles/block).
// ---------------------------------------------------------------------------
__global__ __launch_bounds__(512) void k4_csr_tf(
    const float* __restrict__ nf, const float* __restrict__ Wq, const float* __restrict__ bq,
    const float* __restrict__ Wv, const float* __restrict__ bv,
    unsigned short* __restrict__ qbf, unsigned short* __restrict__ vbf,
    const unsigned int* __restrict__ packed, const int* __restrict__ bbase,
    int* __restrict__ offs, int* __restrict__ ssrc)
{
    __shared__ short8 sB[2][8][64];
    __shared__ float  sbias[128];
    __shared__ int cnt[NPBK];
    __shared__ int lds8[8];
    const int tid = threadIdx.x;

    if (blockIdx.x < NBUCK) {
        const int bk = blockIdx.x;
        const int s0 = bbase[bk], s1 = bbase[bk + 1];
        cnt[tid] = 0;
        __syncthreads();
        for (int e = s0 + tid; e < s1; e += 512)
            atomicAdd(&cnt[packed[e] >> 17], 1);
        __syncthreads();
        int a  = cnt[tid];
        int ex = block_excl_scan_512(a, lds8);
        const int node = (bk << BSH) + tid;
        const int g = s0 + ex;
        if (node < NN) offs[node] = g;
        __syncthreads();
        cnt[tid] = g;                        // becomes cursor
        __syncthreads();
        for (int e = s0 + tid; e < s1; e += 512) {
            unsigned p = packed[e];
            int pos = atomicAdd(&cnt[p >> 17], 1);
            ssrc[pos] = (int)(p & 0x1FFFFu);
        }
        return;
    }

    transform_prep(Wq, bq, Wv, bv, sB, sbias, tid, 512);
    __syncthreads();
    const int wt = TB4 + ((int)blockIdx.x - NBUCK) * 8 + (tid >> 6);
    if (wt < MTILES) transform_tile(nf, qbf, vbf, sB, sbias, wt, tid & 63);
}

// ---------------------------------------------------------------------------
// Gather kernel (UNCHANGED — at the random-gather memory wall):
// one wave per node; 8 lanes per edge (dwordx4 = 8 bf16 channels per lane),
// 8 edge slots, 2-stage rotation. Head logit reduce = ONE dpp add (lane^1).
// ---------------------------------------------------------------------------
__device__ __forceinline__ uint4 ldraw16(const unsigned short* __restrict__ vb,
                                         int src, int s8) {
    return *(const uint4*)((const char*)vb + ((size_t)src << 7) + s8 * 16);
}

__global__ __launch_bounds__(256) void gather_kernel(
    const unsigned short* __restrict__ qb, const unsigned short* __restrict__ vb,
    const float* __restrict__ ak,   // [16][4] row-major: ak[c*4+h]
    const int* __restrict__ offs, const int* __restrict__ ssrc,
    float* __restrict__ out)
{
    const int node = (blockIdx.x * 256 + threadIdx.x) >> 6;
    const int lane = threadIdx.x & 63;
    if (node >= NN) return;
    const int eslot = lane >> 3;     // edge slot 0..7
    const int s8    = lane & 7;      // channel octet 0..7
    const int h     = s8 >> 1;       // head 0..3

    const int start = offs[node];
    const int end   = offs[node + 1];

    if (start >= end) {
        if (lane < 8) {
            float4 z{0.f, 0.f, 0.f, 0.f};
            *(float4*)(out + (size_t)node * 64 + s8 * 8)     = z;
            *(float4*)(out + (size_t)node * 64 + s8 * 8 + 4) = z;
        }
        return;
    }
    const int end1 = end - 1;

    const float c6 = 0.6f * 1.44269504088896f;   // leaky + log2e folded
    const float c4 = 0.4f * 1.44269504088896f;
    float a6[8], a4[8];
    #pragma unroll
    for (int j = 0; j < 8; j++) {
        float k = ak[((s8 & 1) * 8 + j) * 4 + h];
        a6[j] = c6 * k;  a4[j] = c4 * k;
    }

    const uint4 qraw = *(const uint4*)((const char*)qb + ((size_t)node << 7) + s8 * 16);
    float q[8];
    q[0] = bflo(qraw.x); q[1] = bfhi(qraw.x);
    q[2] = bflo(qraw.y); q[3] = bfhi(qraw.y);
    q[4] = bflo(qraw.z); q[5] = bfhi(qraw.z);
    q[6] = bflo(qraw.w); q[7] = bfhi(qraw.w);

    int i0 = ssrc[min(start +     eslot, end1)];
    int i1 = ssrc[min(start + 8 + eslot, end1)];
    uint4 rr0 = ldraw16(vb, i0, s8);
    uint4 rr1 = ldraw16(vb, i1, s8);
    int mi0 = ssrc[min(start + 16 + eslot, end1)];
    int mi1 = ssrc[min(start + 24 + eslot, end1)];

    float acc[8] = {0.f, 0.f, 0.f, 0.f, 0.f, 0.f, 0.f, 0.f};
    float ws = 0.f;

    for (int p = start; p < end; p += 16) {
        {
            float v[8];
            v[0] = bflo(rr0.x); v[1] = bfhi(rr0.x);
            v[2] = bflo(rr0.y); v[3] = bfhi(rr0.y);
            v[4] = bflo(rr0.z); v[5] = bfhi(rr0.z);
            v[6] = bflo(rr0.w); v[7] = bfhi(rr0.w);
            rr0 = ldraw16(vb, mi0, s8);
            mi0 = ssrc[min(p + 32 + eslot, end1)];
            float x = 0.f;
            #pragma unroll
            for (int j = 0; j < 8; j++) {
                float f = q[j] + v[j];
                x = fmaf(f, a6[j], x);
                x = fmaf(fabsf(f), a4[j], x);
            }
            x = dpp_add<0xB1>(x);
            float w = (p + eslot < end) ? __builtin_amdgcn_exp2f(x) : 0.f;
            ws += w;
            #pragma unroll
            for (int j = 0; j < 8; j++) acc[j] = fmaf(w, v[j], acc[j]);
        }
        {
            float v[8];
            v[0] = bflo(rr1.x); v[1] = bfhi(rr1.x);
            v[2] = bflo(rr1.y); v[3] = bfhi(rr1.y);
            v[4] = bflo(rr1.z); v[5] = bfhi(rr1.z);
            v[6] = bflo(rr1.w); v[7] = bfhi(rr1.w);
            rr1 = ldraw16(vb, mi1, s8);
            mi1 = ssrc[min(p + 40 + eslot, end1)];
            float x = 0.f;
            #pragma unroll
            for (int j = 0; j < 8; j++) {
                float f = q[j] + v[j];
                x = fmaf(f, a6[j], x);
                x = fmaf(fabsf(f), a4[j], x);
            }
            x = dpp_add<0xB1>(x);
            float w = (p + 8 + eslot < end) ? __builtin_amdgcn_exp2f(x) : 0.f;
            ws += w;
            #pragma unroll
            for (int j = 0; j < 8; j++) acc[j] = fmaf(w, v[j], acc[j]);
        }
    }

    #pragma unroll
    for (int m = 8; m <= 32; m <<= 1) {
        #pragma unroll
        for (int j = 0; j < 8; j++) acc[j] += __shfl_xor(acc[j], m);
        ws += __shfl_xor(ws, m);
    }

    if (lane < 8) {
        float inv = (ws > 0.f) ? __frcp_rn(ws) : 1.0f;
        float r[8];
        #pragma unroll
        for (int j = 0; j < 8; j++) {
            float t = acc[j] * inv;
            r[j] = fmaxf(t, ALPHA * t);
        }
        *(float4*)(out + (size_t)node * 64 + s8 * 8)     = float4{r[0], r[1], r[2], r[3]};
        *(float4*)(out + (size_t)node * 64 + s8 * 8 + 4) = float4{r[4], r[5], r[6], r[7]};
    }
}

extern "C" void kernel_launch(void* const* d_in, const int* in_sizes, int n_in,
                              void* d_out, int out_size, void* d_ws, size_t ws_size,
                              hipStream_t stream) {
    const float* nf   = (const float*)d_in[0];
    const float* Wq   = (const float*)d_in[1];
    const float* bq   = (const float*)d_in[2];
    const float* Wv   = (const float*)d_in[3];
    const float* bv   = (const float*)d_in[4];
    const float* ak   = (const float*)d_in[5];
    const int*   esrc = (const int*)d_in[6];
    const int*   etgt = (const int*)d_in[7];
    float* out = (float*)d_out;

    // workspace layout:
    //   qbf:     NN*64      u16  (12.8 MB)
    //   vbf:     NN*64      u16  (12.8 MB)
    //   offs:    NN+1       i32
    //   ssrc:    NE         i32  (6.4 MB)
    //   packed:  NE         u32  (6.4 MB)
    //   hist:    NPB*NBUCK  i32  (200 KB)
    //   colbase: NPB*NBUCK  i32  (200 KB)
    //   bbase:   NBUCK+1    i32
    unsigned short* qbf     = (unsigned short*)d_ws;
    unsigned short* vbf     = qbf + (size_t)NN * 64;
    int*            offs    = (int*)(vbf + (size_t)NN * 64);
    int*            ssrc    = offs + (NN + 1);
    unsigned int*   packed  = (unsigned int*)(ssrc + NE);
    int*            hist    = (int*)(packed + NE);
    int*            colbase = hist + NPB * NBUCK;
    int*            bbase   = colbase + NPB * NBUCK;

    k1_hist_tf<<<NPB + N1, 256, 0, stream>>>(nf, Wq, bq, Wv, bv, qbf, vbf, etgt, hist);
    k2_colbase_tf<<<NBUCK + N2, 256, 0, stream>>>(nf, Wq, bq, Wv, bv, qbf, vbf,
                                                  hist, bbase, colbase, offs);
    k3_partition_tf<<<NPB + N3, 256, 0, stream>>>(nf, Wq, bq, Wv, bv, qbf, vbf,
                                                  esrc, etgt, colbase, packed);
    k4_csr_tf<<<NBUCK + N4, 512, 0, stream>>>(nf, Wq, bq, Wv, bv, qbf, vbf,
                                              packed, bbase, offs, ssrc);
    gather_kernel<<<(NN * 64 + 255) / 256, 256, 0, stream>>>(qbf, vbf, ak, offs, ssrc, out);
}